// Round 1
// baseline (212.616 us; speedup 1.0000x reference)
//
#include <hip/hip_runtime.h>

// Exact-match lookup of 4M int32 queries in a sorted 8M int32 key table,
// returning aligned values or -1. Strategy: per-launch bucket index in d_ws
// (start[b] = #keys with (key>>shift) < b), then O(1) expected probe per query.

constexpr int DEFAULT_VALUE = -1;

__global__ void build_start_kernel(const int* __restrict__ keys, int K,
                                   unsigned* __restrict__ start,
                                   int shift, unsigned B) {
    int i = blockIdx.x * blockDim.x + threadIdx.x;
    if (i >= K) return;
    unsigned cb = ((unsigned)keys[i]) >> shift;
    // bucket range this thread owns: (bucket(keys[i-1]), bucket(keys[i])]
    // (for i==0: [0, bucket(keys[0])]). Duplicate keys -> empty range.
    unsigned lo_b = (i == 0) ? 0u : ((((unsigned)keys[i - 1]) >> shift) + 1u);
    for (unsigned b = lo_b; b <= cb; ++b) start[b] = (unsigned)i;
    if (i == K - 1) {
        for (unsigned b = cb + 1; b <= B; ++b) start[b] = (unsigned)K;
    }
}

__global__ void lookup_kernel(const int* __restrict__ query,
                              const int* __restrict__ keys,
                              const int* __restrict__ vals,
                              const unsigned* __restrict__ start,
                              int* __restrict__ out,
                              int N, int shift, unsigned Bmask) {
    int i = blockIdx.x * blockDim.x + threadIdx.x;
    if (i >= N) return;
    int q = query[i];
    // Mask is safe: a query that would map out of range cannot be in the
    // table (keys are int32 >= 1), so landing in a wrong bucket just
    // produces the correct miss (-1).
    unsigned b = (((unsigned)q) >> shift) & Bmask;
    unsigned lo = start[b];
    unsigned hi = start[b + 1];
    int r = DEFAULT_VALUE;
    for (unsigned j = lo; j < hi; ++j) {
        if (keys[j] == q) { r = vals[j]; break; }
    }
    out[i] = r;
}

// Fallback if workspace is too small for the bucket index: plain binary search
// (searchsorted 'left' semantics).
__global__ void lookup_bsearch_kernel(const int* __restrict__ query,
                                      const int* __restrict__ keys,
                                      const int* __restrict__ vals,
                                      int* __restrict__ out,
                                      int N, int K) {
    int i = blockIdx.x * blockDim.x + threadIdx.x;
    if (i >= N) return;
    int q = query[i];
    int lo = 0, hi = K;  // first index with key >= q
    while (lo < hi) {
        int mid = (lo + hi) >> 1;
        if (keys[mid] < q) lo = mid + 1; else hi = mid;
    }
    int r = DEFAULT_VALUE;
    if (lo < K && keys[lo] == q) r = vals[lo];
    out[i] = r;
}

extern "C" void kernel_launch(void* const* d_in, const int* in_sizes, int n_in,
                              void* d_out, int out_size, void* d_ws, size_t ws_size,
                              hipStream_t stream) {
    const int* query = (const int*)d_in[0];
    const int* keys  = (const int*)d_in[1];
    const int* vals  = (const int*)d_in[2];
    int* out = (int*)d_out;
    const int N = in_sizes[0];
    const int K = in_sizes[1];
    const int tb = 256;

    // Pick the finest bucket granularity that fits the workspace:
    // need ((1 << (31 - shift)) + 1) * 4 bytes.
    int shift = 7;  // 2^24 buckets = 64 MB + 4 if it fits
    while (shift < 28 && ((size_t)4 << (31 - shift)) + 4 > ws_size) shift++;

    if (((size_t)4 << (31 - shift)) + 4 <= ws_size) {
        unsigned B = 1u << (31 - shift);
        unsigned* start = (unsigned*)d_ws;
        build_start_kernel<<<(K + tb - 1) / tb, tb, 0, stream>>>(keys, K, start, shift, B);
        lookup_kernel<<<(N + tb - 1) / tb, tb, 0, stream>>>(query, keys, vals, start,
                                                            out, N, shift, B - 1);
    } else {
        lookup_bsearch_kernel<<<(N + tb - 1) / tb, tb, 0, stream>>>(query, keys, vals,
                                                                    out, N, K);
    }
}

// Round 2
// 166.899 us; speedup vs baseline: 1.2739x; 1.2739x over previous
//
#include <hip/hip_runtime.h>

// Exact-match lookup of 4M int32 queries in a sorted 8M int32 key table.
// Round 2: single-probe bucket table. d_ws holds B buckets of 16B each:
//   count==0: {0,0,0,0}
//   count==1: {key0,val0,0,0}
//   count==2: {key0,val0,key1,val1}
//   count>=3: {SENTINEL, start, end, 0}  -> scan original keys/vals[start,end)
// Queries are >=1 so neither 0 (empty) nor SENTINEL (INT_MIN) can false-match.
// First-match order preserved for duplicate keys (k0 checked before k1; scan
// ascending). Build: one pass, each entry written by exactly one thread
// (last-of-bucket writes the entry; first-of-bucket zero-fills the empty gap
// before it) -> deterministic, no atomics, no memset.

constexpr int SENTINEL = (int)0x80000000;  // INT_MIN, not a valid key

__global__ void build_table_kernel(const int* __restrict__ keys,
                                   const int* __restrict__ vals, int K,
                                   int4* __restrict__ table,
                                   int shift, unsigned B) {
    int i = blockIdx.x * blockDim.x + threadIdx.x;
    if (i >= K) return;
    unsigned b  = ((unsigned)keys[i]) >> shift;
    unsigned bn = (i + 1 < K) ? (((unsigned)keys[i + 1]) >> shift) : B;

    // first-of-bucket: zero-fill empty buckets before mine
    if (i == 0) {
        for (unsigned e = 0; e < b; ++e) table[e] = make_int4(0, 0, 0, 0);
    } else {
        unsigned bp = ((unsigned)keys[i - 1]) >> shift;
        if (bp != b) {
            for (unsigned e = bp + 1; e < b; ++e) table[e] = make_int4(0, 0, 0, 0);
        }
    }

    // last-of-bucket: write this bucket's entry (+ trailing empties at the end)
    if (bn != b) {
        int first = i;
        while (first > 0 && (((unsigned)keys[first - 1]) >> shift) == b) --first;
        int cnt = i - first + 1;
        int4 e;
        if (cnt == 1)      e = make_int4(keys[i], vals[i], 0, 0);
        else if (cnt == 2) e = make_int4(keys[first], vals[first], keys[i], vals[i]);
        else               e = make_int4(SENTINEL, first, i + 1, 0);
        table[b] = e;
        if (i == K - 1) {
            for (unsigned t = b + 1; t < B; ++t) table[t] = make_int4(0, 0, 0, 0);
        }
    }
}

__global__ void lookup16_kernel(const int* __restrict__ query,
                                const int* __restrict__ keys,
                                const int* __restrict__ vals,
                                const int4* __restrict__ table,
                                int* __restrict__ out,
                                int N, int shift, unsigned Bmask) {
    int i = blockIdx.x * blockDim.x + threadIdx.x;
    if (i >= N) return;
    int q = query[i];
    int4 e = table[(((unsigned)q) >> shift) & Bmask];
    int r;
    if (e.x == q) {
        r = e.y;
    } else if (e.x == SENTINEL) {
        r = -1;
        int lo = e.y, hi = e.z;
        for (int j = lo; j < hi; ++j) {
            int k = keys[j];
            if (k >= q) { if (k == q) r = vals[j]; break; }
        }
    } else if (e.z == q) {
        r = e.w;
    } else {
        r = -1;
    }
    out[i] = r;
}

// Fallback for tiny workspace: plain binary search (searchsorted 'left').
__global__ void lookup_bsearch_kernel(const int* __restrict__ query,
                                      const int* __restrict__ keys,
                                      const int* __restrict__ vals,
                                      int* __restrict__ out,
                                      int N, int K) {
    int i = blockIdx.x * blockDim.x + threadIdx.x;
    if (i >= N) return;
    int q = query[i];
    int lo = 0, hi = K;
    while (lo < hi) {
        int mid = (lo + hi) >> 1;
        if (keys[mid] < q) lo = mid + 1; else hi = mid;
    }
    int r = -1;
    if (lo < K && keys[lo] == q) r = vals[lo];
    out[i] = r;
}

extern "C" void kernel_launch(void* const* d_in, const int* in_sizes, int n_in,
                              void* d_out, int out_size, void* d_ws, size_t ws_size,
                              hipStream_t stream) {
    const int* query = (const int*)d_in[0];
    const int* keys  = (const int*)d_in[1];
    const int* vals  = (const int*)d_in[2];
    int* out = (int*)d_out;
    const int N = in_sizes[0];
    const int K = in_sizes[1];
    const int tb = 256;

    // Largest bucket count whose 16B-entry table fits the workspace.
    // B=2^23 (shift 8) -> 128 MB table, ~1 key/bucket, ~0.4% overflow buckets.
    int logB = 23;
    while (logB > 18 && ((size_t)16 << logB) > ws_size) logB--;

    if (((size_t)16 << logB) <= ws_size) {
        unsigned B = 1u << logB;
        int shift = 31 - logB;
        int4* table = (int4*)d_ws;
        build_table_kernel<<<(K + tb - 1) / tb, tb, 0, stream>>>(keys, vals, K,
                                                                 table, shift, B);
        lookup16_kernel<<<(N + tb - 1) / tb, tb, 0, stream>>>(query, keys, vals,
                                                              table, out, N,
                                                              shift, B - 1);
    } else {
        lookup_bsearch_kernel<<<(N + tb - 1) / tb, tb, 0, stream>>>(query, keys, vals,
                                                                    out, N, K);
    }
}